// Round 2
// baseline (411.622 us; speedup 1.0000x reference)
//
#include <hip/hip_runtime.h>
#include <math.h>

#define DDIM 4096
#define NPAT 16384
#define THRESHOLD 0.8f

// Kernel 1: gated = sigmoid(query @ W^T + b)
// One 64-lane wave per 2 output rows. Query fragment (64 floats) is loaded
// into registers ONCE per wave and reused for both rows -> halves the
// query L1/L2 re-read traffic and the load-issue count per row.
__global__ __launch_bounds__(256) void gate_kernel(
    const float* __restrict__ query,
    const float* __restrict__ W,
    const float* __restrict__ b,
    float* __restrict__ gated)
{
    int gtid = blockIdx.x * blockDim.x + threadIdx.x;
    int wv   = gtid >> 6;          // wave id: 0..2047, handles rows 2wv, 2wv+1
    int lane = threadIdx.x & 63;

    const float4* q4 = (const float4*)query;

    // query fragment: 16 float4 = 64 floats, register-resident
    float4 q[16];
#pragma unroll
    for (int i = 0; i < 16; ++i)
        q[i] = q4[lane + i * 64];

#pragma unroll
    for (int r = 0; r < 2; ++r) {
        int d = wv * 2 + r;
        const float4* Wrow = (const float4*)(W + (size_t)d * DDIM);

        float sum = 0.0f;
#pragma unroll
        for (int i = 0; i < 16; ++i) {
            float4 w = Wrow[lane + i * 64];
            sum += w.x * q[i].x + w.y * q[i].y + w.z * q[i].z + w.w * q[i].w;
        }
#pragma unroll
        for (int off = 32; off > 0; off >>= 1)
            sum += __shfl_down(sum, off, 64);

        if (lane == 0) {
            float x = sum + b[d];
            gated[d] = 1.0f / (1.0f + __expf(-x));
        }
    }
}

// Kernel 2: sims[n] = 1 - mean(|memory[n] - gated|); mask[n] = sims[n] >= 0.8
// One wave per 8 rows. The gated fragment (64 floats, same lane->index map
// every row) is loaded into VGPRs ONCE; per row only the 16 KB memory row is
// loaded (16 float4/lane). Load instructions per row: 32 -> 16, and the
// 256 MB of gated L1/L2 re-reads are gone.
__global__ __launch_bounds__(256) void sims_kernel(
    const float* __restrict__ memory,
    const float* __restrict__ gated,
    float* __restrict__ sims,
    float* __restrict__ mask)
{
    int gtid = blockIdx.x * blockDim.x + threadIdx.x;
    int wv   = gtid >> 6;          // wave id: 0..2047, handles rows 8wv..8wv+7
    int lane = threadIdx.x & 63;

    const float4* g4 = (const float4*)gated;

    // gated fragment: 16 float4 = 64 floats, register-resident
    float4 g[16];
#pragma unroll
    for (int i = 0; i < 16; ++i)
        g[i] = g4[lane + i * 64];

    int n0 = wv * 8;
#pragma unroll 2
    for (int r = 0; r < 8; ++r) {
        int n = n0 + r;
        const float4* mrow = (const float4*)(memory + (size_t)n * DDIM);

        float sum = 0.0f;
#pragma unroll
        for (int i = 0; i < 16; ++i) {
            float4 m = mrow[lane + i * 64];
            sum += fabsf(m.x - g[i].x) + fabsf(m.y - g[i].y)
                 + fabsf(m.z - g[i].z) + fabsf(m.w - g[i].w);
        }

#pragma unroll
        for (int off = 32; off > 0; off >>= 1)
            sum += __shfl_down(sum, off, 64);

        if (lane == 0) {
            float sim = 1.0f - sum * (1.0f / (float)DDIM);
            sims[n] = sim;
            mask[n] = (sim >= THRESHOLD) ? 1.0f : 0.0f;
        }
    }
}

extern "C" void kernel_launch(void* const* d_in, const int* in_sizes, int n_in,
                              void* d_out, int out_size, void* d_ws, size_t ws_size,
                              hipStream_t stream) {
    const float* query  = (const float*)d_in[0];   // [1, D]
    const float* W      = (const float*)d_in[1];   // [D, D]
    const float* b      = (const float*)d_in[2];   // [D]
    const float* memory = (const float*)d_in[3];   // [N, D]

    float* gated = (float*)d_ws;                   // D floats scratch
    float* sims  = (float*)d_out;                  // first N floats
    float* mask  = (float*)d_out + NPAT;           // next N floats (0.0/1.0)

    // Kernel 1: 2048 waves, 2 rows each -> 512 blocks of 256
    {
        gate_kernel<<<512, 256, 0, stream>>>(query, W, b, gated);
    }
    // Kernel 2: 2048 waves, 8 rows each -> 512 blocks of 256
    {
        sims_kernel<<<512, 256, 0, stream>>>(memory, gated, sims, mask);
    }
}

// Round 3
// 375.426 us; speedup vs baseline: 1.0964x; 1.0964x over previous
//
#include <hip/hip_runtime.h>
#include <math.h>

#define DDIM 4096
#define NPAT 16384
#define THRESHOLD 0.8f

typedef float f4 __attribute__((ext_vector_type(4)));

// Kernel 1: gated = sigmoid(query @ W^T + b)
// One wave per output row d (4 rows per 256-thread block, 1024 blocks).
// query (16 KB) is staged in LDS once per block; per row: 16 global float4
// (W, nontemporal stream) + 16 ds_read_b128 (query).
__global__ __launch_bounds__(256) void gate_kernel(
    const float* __restrict__ query,
    const float* __restrict__ W,
    const float* __restrict__ b,
    float* __restrict__ gated)
{
    __shared__ f4 qs[1024];                 // 16 KB
    int t = threadIdx.x;
    const f4* q4 = (const f4*)query;
#pragma unroll
    for (int i = 0; i < 4; ++i)
        qs[t + i * 256] = q4[t + i * 256];
    __syncthreads();

    int wid  = t >> 6;
    int lane = t & 63;
    int d = blockIdx.x * 4 + wid;

    const f4* Wrow = (const f4*)(W + (size_t)d * DDIM);

    float sum = 0.0f;
#pragma unroll
    for (int i = 0; i < 16; ++i) {
        f4 w = __builtin_nontemporal_load(&Wrow[lane + i * 64]);
        f4 q = qs[lane + i * 64];
        sum += w.x * q.x + w.y * q.y + w.z * q.z + w.w * q.w;
    }
#pragma unroll
    for (int off = 32; off > 0; off >>= 1)
        sum += __shfl_down(sum, off, 64);

    if (lane == 0) {
        float x = sum + b[d];
        gated[d] = 1.0f / (1.0f + __expf(-x));
    }
}

// Kernel 2: sims[n] = 1 - mean(|memory[n] - gated|); mask[n] = sims[n] >= 0.8
// One wave per pattern row (4 rows per block, 4096 blocks) — round-1's
// max-TLP shape. gated (16 KB) staged in LDS once per block: per row
// 16 global float4 (memory, nontemporal stream) + 16 ds_read_b128 (gated).
// Load-issue per row halves vs round 1, gated L2 re-read traffic drops 4x,
// and the zero-reuse 256 MB stream no longer thrashes L1/L2.
__global__ __launch_bounds__(256) void sims_kernel(
    const float* __restrict__ memory,
    const float* __restrict__ gated,
    float* __restrict__ sims,
    float* __restrict__ mask)
{
    __shared__ f4 gs[1024];                 // 16 KB
    int t = threadIdx.x;
    const f4* g4 = (const f4*)gated;
#pragma unroll
    for (int i = 0; i < 4; ++i)
        gs[t + i * 256] = g4[t + i * 256];
    __syncthreads();

    int wid  = t >> 6;
    int lane = t & 63;
    int n = blockIdx.x * 4 + wid;

    const f4* mrow = (const f4*)(memory + (size_t)n * DDIM);

    float sum = 0.0f;
#pragma unroll
    for (int i = 0; i < 16; ++i) {
        f4 m = __builtin_nontemporal_load(&mrow[lane + i * 64]);
        f4 g = gs[lane + i * 64];
        sum += fabsf(m.x - g.x) + fabsf(m.y - g.y)
             + fabsf(m.z - g.z) + fabsf(m.w - g.w);
    }

#pragma unroll
    for (int off = 32; off > 0; off >>= 1)
        sum += __shfl_down(sum, off, 64);

    if (lane == 0) {
        float sim = 1.0f - sum * (1.0f / (float)DDIM);
        sims[n] = sim;
        mask[n] = (sim >= THRESHOLD) ? 1.0f : 0.0f;
    }
}

extern "C" void kernel_launch(void* const* d_in, const int* in_sizes, int n_in,
                              void* d_out, int out_size, void* d_ws, size_t ws_size,
                              hipStream_t stream) {
    const float* query  = (const float*)d_in[0];   // [1, D]
    const float* W      = (const float*)d_in[1];   // [D, D]
    const float* b      = (const float*)d_in[2];   // [D]
    const float* memory = (const float*)d_in[3];   // [N, D]

    float* gated = (float*)d_ws;                   // D floats scratch
    float* sims  = (float*)d_out;                  // first N floats
    float* mask  = (float*)d_out + NPAT;           // next N floats (0.0/1.0)

    // Kernel 1: 4096 rows / 4 per block -> 1024 blocks
    {
        gate_kernel<<<1024, 256, 0, stream>>>(query, W, b, gated);
    }
    // Kernel 2: 16384 rows / 4 per block -> 4096 blocks
    {
        sims_kernel<<<4096, 256, 0, stream>>>(memory, gated, sims, mask);
    }
}